// Round 8
// baseline (169.008 us; speedup 1.0000x reference)
//
#include <hip/hip_runtime.h>
#include <hip/hip_bf16.h>

#define NXC 440
#define NYC 500
#define GCELLS (NXC * NYC)            // 220000 (NZ = 1)
#define NWORDS ((GCELLS + 31) / 32)   // 6875 bitmap words
#define MAXV 40000
#define MAXP 32
#define SCANB ((NWORDS + 255) / 256)  // 27 x-slices for k_orred
#define GPB 16                        // bitmaps OR'd per k_orred block
#define TPAD 16                       // ticket stride (ints): 1 counter / 64B line
#define WPT ((NWORDS + 1023) / 1024)  // 7 words per thread in k_scan1

// Expected outputs are bf16-quantized but stored as fp32: round-trip.
__device__ __forceinline__ float bf16r(float x) {
    return __bfloat162float(__float2bfloat16(x));
}

// Linear cell index exactly as the numpy reference (fp32 ops). Invalid -> -1.
__device__ __forceinline__ int point_cell(const float* p) {
    float x = p[0], y = p[1], z = p[2];
    bool valid = (x >= 0.0f) && (x < 70.4f) &&
                 (y >= -40.0f) && (y < 40.0f) &&
                 (z >= -3.0f) && (z < 1.0f);
    if (!valid) return -1;
    int cx = (int)floorf(x / 0.16f);
    int cy = (int)floorf((y + 40.0f) / 0.16f);
    // z in [-3,1) -> cz == 0 always (NZ = 1)
    cx = min(max(cx, 0), NXC - 1);
    cy = min(max(cy, 0), NYC - 1);
    return cy * NXC + cx;
}

// Pass 1: per-block LDS occupancy bitmap + cellid cache. Also zero-inits occ
// and tickets (runs before k_orred / k_scatter in stream order) -> no memset.
__global__ __launch_bounds__(256) void k_cell(const float* pts, int* cellid,
                                              unsigned* bitmaps, unsigned* occ,
                                              int* ticket, int n, int G) {
    __shared__ unsigned bm[NWORDS];   // 27.5 KB
    for (int w = threadIdx.x; w < NWORDS; w += 256) bm[w] = 0u;
    __syncthreads();
    int stride = G * 256;
    int tid = blockIdx.x * 256 + threadIdx.x;
    for (int i = tid; i < n; i += stride) {
        int cell = point_cell(pts + (size_t)i * 5);
        if (cellid) cellid[i] = cell;
        if (cell >= 0) atomicOr(&bm[cell >> 5], 1u << (cell & 31));
    }
    // init for later kernels (grid-strided; tiny)
    for (int idx = tid; idx < NWORDS; idx += stride) occ[idx] = 0u;
    for (int idx = tid; idx < MAXV * TPAD; idx += stride) ticket[idx] = 0;
    __syncthreads();
    unsigned* dst = bitmaps + (size_t)blockIdx.x * NWORDS;
    for (int w = threadIdx.x; w < NWORDS; w += 256) dst[w] = bm[w];
}

// Parallel OR-reduce: block (bx, by) ORs bitmaps [by*GPB, (by+1)*GPB) over its
// 256-word slice, one atomicOr per word into occ (zeroed in k_cell).
__global__ __launch_bounds__(256) void k_orred(const unsigned* bitmaps, unsigned* occ) {
    int w = blockIdx.x * 256 + threadIdx.x;
    if (w >= NWORDS) return;
    const unsigned* src = bitmaps + (size_t)blockIdx.y * GPB * NWORDS + w;
    unsigned o = 0u;
    #pragma unroll
    for (int g = 0; g < GPB; ++g) o |= src[(size_t)g * NWORDS];
    if (o) atomicOr(&occ[w], o);
}

// Single-block scan: popcount + exclusive scan over all 6875 words, emit
// wpre + coords for kept voxels, zero coords tail if under-occupied.
__global__ __launch_bounds__(1024) void k_scan1(const unsigned* occ, int* wpre,
                                                float* out_coords) {
    int t = threadIdx.x;
    int base_w = t * WPT;
    unsigned w[WPT];
    int c = 0;
    #pragma unroll
    for (int k = 0; k < WPT; ++k) {
        int ww = base_w + k;
        w[k] = (ww < NWORDS) ? occ[ww] : 0u;
        c += __popc(w[k]);
    }
    __shared__ int s[1024];
    s[t] = c;
    __syncthreads();
    for (int d = 1; d < 1024; d <<= 1) {
        int v = (t >= d) ? s[t - d] : 0;
        __syncthreads();
        s[t] += v;
        __syncthreads();
    }
    int vid = s[t] - c;            // exclusive prefix of this thread's words
    int total = s[1023];           // total occupied cells
    #pragma unroll
    for (int k = 0; k < WPT; ++k) {
        int ww = base_w + k;
        if (ww < NWORDS) {
            wpre[ww] = vid;
            unsigned m = w[k];
            while (m && vid < MAXV) {
                int bit = __ffs(m) - 1;
                m &= m - 1u;
                int cell = ww * 32 + bit;
                int cy = cell / NXC, cx = cell - cy * NXC;
                float* oc = out_coords + (size_t)vid * 3;
                oc[0] = 0.0f;
                oc[1] = bf16r((float)cy);
                oc[2] = bf16r((float)cx);
                ++vid;
            }
            vid += __popc(m);      // bits skipped past MAXV still advance vid
        }
    }
    // robustness: zero coords rows for voxel slots beyond total occupancy
    for (int vz = total + t; vz < MAXV; vz += 1024) {
        float* oc = out_coords + (size_t)vz * 3;
        oc[0] = 0.0f; oc[1] = 0.0f; oc[2] = 0.0f;
    }
}

// Scatter point indices into fixed-stride per-voxel segments (kept voxels only).
// ticket padded to 1 counter / 64B line (kills cross-XCD false sharing).
__global__ __launch_bounds__(256) void k_scatter(const float* pts, const int* cellid,
                                                 const unsigned* occ, const int* wpre,
                                                 int* ticket, int* seg, int S, int n) {
    int i = blockIdx.x * 256 + threadIdx.x;
    if (i >= n) return;
    int cell = cellid ? cellid[i] : point_cell(pts + (size_t)i * 5);
    if (cell < 0) return;
    int w = cell >> 5, b = cell & 31;
    int vid = wpre[w] + __popc(occ[w] & ((1u << b) - 1u));
    if (vid >= MAXV) return;
    int t = atomicAdd(&ticket[(size_t)vid * TPAD], 1);
    if (t < S) seg[(size_t)vid * S + t] = i;
}

// One wave per voxel: rank by original index (stable), gather feats, write ALL
// 32 slots (zeros for empty ranks) + num_points. No output memset needed.
__global__ __launch_bounds__(256) void k_fill(const float* pts, const int* ticket,
                                              const int* seg, int S,
                                              float* out_vox, float* out_np) {
    __shared__ int slot[4][MAXP];
    int wave = threadIdx.x >> 6, lane = threadIdx.x & 63;
    int v = blockIdx.x * 4 + wave;     // MAXV % 4 == 0 -> always in range
    int ntot = ticket[(size_t)v * TPAD];
    int nn = min(ntot, S);             // S >= 32; P(cell count > S) ~ 0
    int m = min(nn, MAXP);
    int myidx = (lane < nn) ? seg[(size_t)v * S + lane] : 0x7fffffff;
    int rank = 0;
    for (int j = 0; j < nn; ++j) {
        int ej = __shfl(myidx, j, 64);
        rank += (ej < myidx) ? 1 : 0;
    }
    if (lane < nn && rank < MAXP) slot[wave][rank] = myidx;
    __syncthreads();   // order LDS scatter before readback (all threads reach)
    if (lane < MAXP) {
        float* dst = out_vox + ((size_t)v * MAXP + lane) * 5;
        if (lane < m) {
            const float* src = pts + (size_t)slot[wave][lane] * 5;
            #pragma unroll
            for (int k = 0; k < 5; ++k) dst[k] = bf16r(src[k]);
        } else {
            #pragma unroll
            for (int k = 0; k < 5; ++k) dst[k] = 0.0f;
        }
    }
    if (lane == 0) out_np[v] = bf16r((float)m);
}

extern "C" void kernel_launch(void* const* d_in, const int* in_sizes, int n_in,
                              void* d_out, int out_size, void* d_ws, size_t ws_size,
                              hipStream_t stream) {
    const float* pts = (const float*)d_in[0];
    int n = in_sizes[0] / 5;

    float* out = (float*)d_out;   // fp32 storage, bf16-precision values
    float* out_vox    = out;                                   // MAXV*32*5
    float* out_coords = out + (size_t)MAXV * MAXP * 5;         // MAXV*3
    float* out_np     = out_coords + (size_t)MAXV * 3;         // MAXV

    // ws ints: cellid[n]? + bitmaps[G*NWORDS] + occ[NWORDS] + ticket[MAXV*TPAD]
    //          + wpre[NWORDS] + seg[MAXV*S]   (~28 MB at G=256,S=64,cid)
    const size_t fixed_ints = 2 * (size_t)NWORDS + (size_t)MAXV * TPAD;
    int G = 64, S = 32; bool use_cid = false;
    {
        auto fits = [&](int g, int s, bool cid) {
            size_t ints = fixed_ints + (size_t)g * NWORDS + (size_t)MAXV * s
                        + (cid ? (size_t)n : 0);
            return ints * sizeof(int) <= ws_size;
        };
        struct Cfg { int g, s; bool cid; };
        const Cfg cfgs[] = {
            {256, 64, true}, {256, 48, true}, {128, 48, true},
            {128, 40, false}, {64, 32, false}, {32, 32, false},
        };
        for (const Cfg& c : cfgs) {
            if (fits(c.g, c.s, c.cid)) { G = c.g; S = c.s; use_cid = c.cid; break; }
        }
    }

    int* ws = (int*)d_ws;
    int* cellid        = use_cid ? ws : nullptr;                       // n (optional)
    unsigned* bitmaps  = (unsigned*)(ws + (use_cid ? (size_t)n : 0));  // G*NWORDS
    unsigned* occ      = bitmaps + (size_t)G * NWORDS;                 // NWORDS (zeroed in k_cell)
    int* ticket        = (int*)(occ + NWORDS);                         // MAXV*TPAD (zeroed in k_cell)
    int* wpre          = ticket + (size_t)MAXV * TPAD;                 // NWORDS
    int* seg           = wpre + NWORDS;                                // MAXV * S

    int nb = (n + 255) / 256;
    k_cell<<<G, 256, 0, stream>>>(pts, cellid, bitmaps, occ, ticket, n, G);
    k_orred<<<dim3(SCANB, G / GPB), 256, 0, stream>>>(bitmaps, occ);
    k_scan1<<<1, 1024, 0, stream>>>(occ, wpre, out_coords);
    k_scatter<<<nb, 256, 0, stream>>>(pts, cellid, occ, wpre, ticket, seg, S, n);
    k_fill<<<(MAXV + 3) / 4, 256, 0, stream>>>(pts, ticket, seg, S, out_vox, out_np);
}

// Round 9
// 162.217 us; speedup vs baseline: 1.0419x; 1.0419x over previous
//
#include <hip/hip_runtime.h>
#include <hip/hip_bf16.h>

#define NXC 440
#define NYC 500
#define GCELLS (NXC * NYC)            // 220000 (NZ = 1)
#define NWORDS ((GCELLS + 31) / 32)   // 6875 bitmap words (6875*32 == 220000 exactly)
#define MAXV 40000
#define MAXP 32
#define SCANB ((NWORDS + 255) / 256)  // 27 x-slices for k_orred
#define GPB 16                        // bitmaps OR'd per k_orred block
#define TPAD 16                       // ticket stride (ints): 1 counter / 64B line
#define WPT ((NWORDS + 1023) / 1024)  // 7 words per thread in k_scan1

// Expected outputs are bf16-quantized but stored as fp32: round-trip.
__device__ __forceinline__ float bf16r(float x) {
    return __bfloat162float(__float2bfloat16(x));
}

// Cell from coords, matching numpy fp32 semantics. Invalid -> -1.
__device__ __forceinline__ int cell_from(float x, float y, float z) {
    bool valid = (x >= 0.0f) && (x < 70.4f) &&
                 (y >= -40.0f) && (y < 40.0f) &&
                 (z >= -3.0f) && (z < 1.0f);
    if (!valid) return -1;
    int cx = (int)floorf(x / 0.16f);
    int cy = (int)floorf((y + 40.0f) / 0.16f);
    // z in [-3,1) -> cz == 0 always (NZ = 1)
    cx = min(max(cx, 0), NXC - 1);
    cy = min(max(cy, 0), NYC - 1);
    return cy * NXC + cx;
}

__device__ __forceinline__ int point_cell(const float* p) {
    return cell_from(p[0], p[1], p[2]);
}

// Pass 1: per-block LDS occupancy bitmap + cellid cache, 4 points/thread/iter
// via float4 loads (MLP). Also zero-inits occ + tickets (no separate memset).
__global__ __launch_bounds__(256) void k_cell(const float* pts, int* cellid,
                                              unsigned* bitmaps, unsigned* occ,
                                              int* ticket, int n, int G) {
    __shared__ unsigned bm[NWORDS];   // 27.5 KB -> LDS caps at 5 blocks/CU; G=512 ~ 2/CU
    for (int w = threadIdx.x; w < NWORDS; w += 256) bm[w] = 0u;
    __syncthreads();
    int tid = blockIdx.x * 256 + threadIdx.x;
    int stride = G * 256;
    int ngrp = n >> 2;                // groups of 4 points (80 B, 16B-aligned)
    for (int g = tid; g < ngrp; g += stride) {
        const float4* p4 = (const float4*)(pts + (size_t)g * 20);
        float4 a = p4[0], b = p4[1], c = p4[2], d = p4[3], e = p4[4];
        // layout: pt0={a.x,a.y,a.z,a.w,b.x} pt1={b.y,b.z,b.w,c.x,c.y}
        //         pt2={c.z,c.w,d.x,d.y,d.z} pt3={d.w,e.x,e.y,e.z,e.w}
        int4 cc;
        cc.x = cell_from(a.x, a.y, a.z);
        cc.y = cell_from(b.y, b.z, b.w);
        cc.z = cell_from(c.z, c.w, d.x);
        cc.w = cell_from(d.w, e.x, e.y);
        if (cellid) ((int4*)cellid)[g] = cc;
        if (cc.x >= 0) atomicOr(&bm[cc.x >> 5], 1u << (cc.x & 31));
        if (cc.y >= 0) atomicOr(&bm[cc.y >> 5], 1u << (cc.y & 31));
        if (cc.z >= 0) atomicOr(&bm[cc.z >> 5], 1u << (cc.z & 31));
        if (cc.w >= 0) atomicOr(&bm[cc.w >> 5], 1u << (cc.w & 31));
    }
    for (int i = (ngrp << 2) + tid; i < n; i += stride) {   // tail (n % 4)
        int cell = point_cell(pts + (size_t)i * 5);
        if (cellid) cellid[i] = cell;
        if (cell >= 0) atomicOr(&bm[cell >> 5], 1u << (cell & 31));
    }
    // zero-init for later kernels (runs before their dispatches in stream order)
    for (int idx = tid; idx < NWORDS; idx += stride) occ[idx] = 0u;
    for (int idx = tid; idx < MAXV * TPAD; idx += stride) ticket[idx] = 0;
    __syncthreads();
    unsigned* dst = bitmaps + (size_t)blockIdx.x * NWORDS;
    for (int w = threadIdx.x; w < NWORDS; w += 256) dst[w] = bm[w];
}

// Parallel OR-reduce: block (bx, by) ORs bitmaps [by*GPB, (by+1)*GPB) over its
// 256-word slice, one atomicOr per word into occ (zeroed in k_cell).
__global__ __launch_bounds__(256) void k_orred(const unsigned* bitmaps, unsigned* occ) {
    int w = blockIdx.x * 256 + threadIdx.x;
    if (w >= NWORDS) return;
    const unsigned* src = bitmaps + (size_t)blockIdx.y * GPB * NWORDS + w;
    unsigned o = 0u;
    #pragma unroll
    for (int g = 0; g < GPB; ++g) o |= src[(size_t)g * NWORDS];
    if (o) atomicOr(&occ[w], o);
}

// Single-block scan: popcount + exclusive scan over all 6875 words, emit
// wpre + coords for kept voxels, zero coords tail if under-occupied.
__global__ __launch_bounds__(1024) void k_scan1(const unsigned* occ, int* wpre,
                                                float* out_coords) {
    int t = threadIdx.x;
    int base_w = t * WPT;
    unsigned w[WPT];
    int c = 0;
    #pragma unroll
    for (int k = 0; k < WPT; ++k) {
        int ww = base_w + k;
        w[k] = (ww < NWORDS) ? occ[ww] : 0u;
        c += __popc(w[k]);
    }
    __shared__ int s[1024];
    s[t] = c;
    __syncthreads();
    for (int d = 1; d < 1024; d <<= 1) {
        int v = (t >= d) ? s[t - d] : 0;
        __syncthreads();
        s[t] += v;
        __syncthreads();
    }
    int vid = s[t] - c;            // exclusive prefix of this thread's words
    int total = s[1023];           // total occupied cells
    #pragma unroll
    for (int k = 0; k < WPT; ++k) {
        int ww = base_w + k;
        if (ww < NWORDS) {
            wpre[ww] = vid;
            unsigned m = w[k];
            while (m && vid < MAXV) {
                int bit = __ffs(m) - 1;
                m &= m - 1u;
                int cell = ww * 32 + bit;
                int cy = cell / NXC, cx = cell - cy * NXC;
                float* oc = out_coords + (size_t)vid * 3;
                oc[0] = 0.0f;
                oc[1] = bf16r((float)cy);
                oc[2] = bf16r((float)cx);
                ++vid;
            }
            vid += __popc(m);      // bits past MAXV still advance vid
        }
    }
    // robustness: zero coords rows for voxel slots beyond total occupancy
    for (int vz = total + t; vz < MAXV; vz += 1024) {
        float* oc = out_coords + (size_t)vz * 3;
        oc[0] = 0.0f; oc[1] = 0.0f; oc[2] = 0.0f;
    }
}

// Scatter point indices into fixed-stride per-voxel segments (kept voxels only).
// ticket padded to 1 counter / 64B line (kills cross-XCD false sharing).
__global__ __launch_bounds__(256) void k_scatter(const float* pts, const int* cellid,
                                                 const unsigned* occ, const int* wpre,
                                                 int* ticket, int* seg, int S, int n) {
    int i = blockIdx.x * 256 + threadIdx.x;
    if (i >= n) return;
    int cell = cellid ? cellid[i] : point_cell(pts + (size_t)i * 5);
    if (cell < 0) return;
    int w = cell >> 5, b = cell & 31;
    int vid = wpre[w] + __popc(occ[w] & ((1u << b) - 1u));
    if (vid >= MAXV) return;
    int t = atomicAdd(&ticket[(size_t)vid * TPAD], 1);
    if (t < S) seg[(size_t)vid * S + t] = i;
}

// One wave per voxel: rank by original index (stable), gather feats, write ALL
// 32 slots (zeros for empty ranks) + num_points. No output memset needed.
__global__ __launch_bounds__(256) void k_fill(const float* pts, const int* ticket,
                                              const int* seg, int S,
                                              float* out_vox, float* out_np) {
    __shared__ int slot[4][MAXP];
    int wave = threadIdx.x >> 6, lane = threadIdx.x & 63;
    int v = blockIdx.x * 4 + wave;     // MAXV % 4 == 0 -> always in range
    int ntot = ticket[(size_t)v * TPAD];
    int nn = min(ntot, S);             // S >= 32; P(cell count > S) ~ 0
    int m = min(nn, MAXP);
    int myidx = (lane < nn) ? seg[(size_t)v * S + lane] : 0x7fffffff;
    int rank = 0;
    for (int j = 0; j < nn; ++j) {
        int ej = __shfl(myidx, j, 64);
        rank += (ej < myidx) ? 1 : 0;
    }
    if (lane < nn && rank < MAXP) slot[wave][rank] = myidx;
    __syncthreads();   // order LDS scatter before readback (all threads reach)
    if (lane < MAXP) {
        float* dst = out_vox + ((size_t)v * MAXP + lane) * 5;
        if (lane < m) {
            const float* src = pts + (size_t)slot[wave][lane] * 5;
            #pragma unroll
            for (int k = 0; k < 5; ++k) dst[k] = bf16r(src[k]);
        } else {
            #pragma unroll
            for (int k = 0; k < 5; ++k) dst[k] = 0.0f;
        }
    }
    if (lane == 0) out_np[v] = bf16r((float)m);
}

extern "C" void kernel_launch(void* const* d_in, const int* in_sizes, int n_in,
                              void* d_out, int out_size, void* d_ws, size_t ws_size,
                              hipStream_t stream) {
    const float* pts = (const float*)d_in[0];
    int n = in_sizes[0] / 5;

    float* out = (float*)d_out;   // fp32 storage, bf16-precision values
    float* out_vox    = out;                                   // MAXV*32*5
    float* out_coords = out + (size_t)MAXV * MAXP * 5;         // MAXV*3
    float* out_np     = out_coords + (size_t)MAXV * 3;         // MAXV

    // ws ints: cellid[n]? + bitmaps[G*NWORDS] + occ[NWORDS] + ticket[MAXV*TPAD]
    //          + wpre[NWORDS] + seg[MAXV*S]
    const size_t fixed_ints = 2 * (size_t)NWORDS + (size_t)MAXV * TPAD;
    int G = 64, S = 32; bool use_cid = false;
    {
        auto fits = [&](int g, int s, bool cid) {
            size_t ints = fixed_ints + (size_t)g * NWORDS + (size_t)MAXV * s
                        + (cid ? (size_t)n : 0);
            return ints * sizeof(int) <= ws_size;
        };
        struct Cfg { int g, s; bool cid; };
        const Cfg cfgs[] = {
            {512, 64, true},   // k_cell at 2 blocks/CU (LDS 27.5KB caps 5/CU)
            {256, 64, true}, {256, 48, true}, {128, 48, true},
            {128, 40, false}, {64, 32, false}, {32, 32, false},
        };
        for (const Cfg& c : cfgs) {
            if (fits(c.g, c.s, c.cid)) { G = c.g; S = c.s; use_cid = c.cid; break; }
        }
    }

    int* ws = (int*)d_ws;
    int* cellid        = use_cid ? ws : nullptr;                       // n (optional)
    unsigned* bitmaps  = (unsigned*)(ws + (use_cid ? (size_t)n : 0));  // G*NWORDS
    unsigned* occ      = bitmaps + (size_t)G * NWORDS;                 // NWORDS (zeroed in k_cell)
    int* ticket        = (int*)(occ + NWORDS);                         // MAXV*TPAD (zeroed in k_cell)
    int* wpre          = ticket + (size_t)MAXV * TPAD;                 // NWORDS
    int* seg           = wpre + NWORDS;                                // MAXV * S

    int nb = (n + 255) / 256;
    k_cell<<<G, 256, 0, stream>>>(pts, cellid, bitmaps, occ, ticket, n, G);
    k_orred<<<dim3(SCANB, G / GPB), 256, 0, stream>>>(bitmaps, occ);
    k_scan1<<<1, 1024, 0, stream>>>(occ, wpre, out_coords);
    k_scatter<<<nb, 256, 0, stream>>>(pts, cellid, occ, wpre, ticket, seg, S, n);
    k_fill<<<(MAXV + 3) / 4, 256, 0, stream>>>(pts, ticket, seg, S, out_vox, out_np);
}